// Round 1
// baseline (193.550 us; speedup 1.0000x reference)
//
#include <hip/hip_runtime.h>

#define NPTS 131072
#define NE 8
#define DIN 90
#define NH 256
#define DO4 4
#define HPITCH 264   // bf16 elems per sH row: 16B-aligned rows, 2-way-max bank pattern

typedef __attribute__((ext_vector_type(8))) short bf16x8;
typedef __attribute__((ext_vector_type(4))) float f32x4;
typedef __attribute__((ext_vector_type(2))) unsigned int u32x2;

__device__ __forceinline__ unsigned short f2bf(float f) {
  unsigned int u = __float_as_uint(f);
  u += 0x7fffu + ((u >> 16) & 1u);   // RNE
  return (unsigned short)(u >> 16);
}

// W1 (E,DIN,H) fp32 -> W1T [e][hcol 0..255][k 0..95] bf16 (k>=90 zero)
__global__ __launch_bounds__(256) void prep_w1(const float* __restrict__ W1,
                                               unsigned short* __restrict__ W1T) {
  int idx = blockIdx.x * 256 + threadIdx.x;
  if (idx >= NE * NH * 96) return;
  int kp = idx % 96;
  int n  = (idx / 96) % NH;
  int e  = idx / (96 * NH);
  float v = (kp < DIN) ? W1[((size_t)e * DIN + kp) * NH + n] : 0.f;
  W1T[idx] = f2bf(v);
}

// W2 (E,H,DOUT) fp32 -> W2T [e][o 0..15][k 0..255] bf16 (o>=4 zero)
__global__ __launch_bounds__(256) void prep_w2(const float* __restrict__ W2,
                                               unsigned short* __restrict__ W2T) {
  int idx = blockIdx.x * 256 + threadIdx.x;
  if (idx >= NE * 16 * NH) return;
  int k = idx % NH;
  int o = (idx / NH) % 16;
  int e = idx / (16 * NH);
  float v = (o < DO4) ? W2[((size_t)e * NH + k) * DO4 + o] : 0.f;
  W2T[idx] = f2bf(v);
}

__global__ __launch_bounds__(256, 2) void meganerf_main(
    const float* __restrict__ x, const float* __restrict__ cent,
    const float* __restrict__ b1, const float* __restrict__ b2,
    const unsigned short* __restrict__ W1T, const unsigned short* __restrict__ W2T,
    float* __restrict__ out) {
  __shared__ unsigned short sH[64 * HPITCH];   // h tile, bf16, row-major [row][hcol] (33792 B)
  __shared__ float sW[NE][64];                 // per-point expert weights
  __shared__ float sB2[64][DO4];               // sum_e w*b2
  __shared__ float sOutP[4][64][DO4];          // per-wave layer-2 partials

  const int t   = threadIdx.x;
  const int lane = t & 63;
  const int wid = t >> 6;
  const int l15 = lane & 15;
  const int l4  = lane >> 4;
  const int row0 = blockIdx.x * 64;

  // ---- feat fragments (MFMA B operand: B[k][n=row]), held in regs for all experts ----
  bf16x8 bfr[4][3];
#pragma unroll
  for (int nf = 0; nf < 4; ++nf) {
    const float* gr = x + (size_t)(row0 + 16 * nf + l15) * 93 + 3;
#pragma unroll
    for (int ks = 0; ks < 3; ++ks) {
      const int kb = 32 * ks + 8 * l4;
      bf16x8 a;
#pragma unroll
      for (int j = 0; j < 8; ++j) {
        int k = kb + j;
        float v = (k < DIN) ? gr[k] : 0.f;
        a[j] = (short)f2bf(v);
      }
      bfr[nf][ks] = a;
    }
  }

  // ---- per-point expert weights (threads 0..63, one point each) ----
  if (t < 64) {
    const float* gx = x + (size_t)(row0 + t) * 93;
    float px = gx[0], py = gx[1], pz = gx[2];
    float dist[NE], inv[NE];
    float mind = 3.4e38f;
#pragma unroll
    for (int e = 0; e < NE; ++e) {
      float dx = px - cent[e * 3 + 0];
      float dy = py - cent[e * 3 + 1];
      float dz = pz - cent[e * 3 + 2];
      float d2 = dx * dx + dy * dy + dz * dz;
      float d = sqrtf(fmaxf(d2, 0.f));
      dist[e] = d;
      inv[e] = 1.f / (d + 1e-8f);
      mind = fminf(mind, d);
    }
    float s = 0.f;
#pragma unroll
    for (int e = 0; e < NE; ++e) {
      if (dist[e] > 2.0f * mind) inv[e] = 0.f;
      s += inv[e];
    }
    float rs = 1.f / s;
    float bb[4] = {0.f, 0.f, 0.f, 0.f};
#pragma unroll
    for (int e = 0; e < NE; ++e) {
      float w = inv[e] * rs;
      sW[e][t] = w;
#pragma unroll
      for (int o = 0; o < 4; ++o) bb[o] += w * b2[e * 4 + o];
    }
#pragma unroll
    for (int o = 0; o < 4; ++o) sB2[t][o] = bb[o];
  }
  __syncthreads();

  f32x4 facc[4] = {{0.f, 0.f, 0.f, 0.f}, {0.f, 0.f, 0.f, 0.f},
                   {0.f, 0.f, 0.f, 0.f}, {0.f, 0.f, 0.f, 0.f}};

  for (int e = 0; e < NE; ++e) {
    float wv[4];
#pragma unroll
    for (int nf = 0; nf < 4; ++nf) wv[nf] = sW[e][16 * nf + l15];

    // ---- layer 1: h^T = W1^T * feat^T  (D rows = hcols, D cols = point rows) ----
#pragma unroll
    for (int c = 0; c < 2; ++c) {
      const int colbase = 128 * c + 32 * wid;   // hcol base for this wave/chunk
      f32x4 b1v[2];
#pragma unroll
      for (int mf = 0; mf < 2; ++mf)
        b1v[mf] = *(const f32x4*)(b1 + e * NH + colbase + 16 * mf + 4 * l4);
      f32x4 acc[2][4];
#pragma unroll
      for (int mf = 0; mf < 2; ++mf)
#pragma unroll
        for (int nf = 0; nf < 4; ++nf) acc[mf][nf] = b1v[mf];  // bias pre-loaded
#pragma unroll
      for (int ks = 0; ks < 3; ++ks) {
        bf16x8 w1f[2];
#pragma unroll
        for (int mf = 0; mf < 2; ++mf)
          w1f[mf] = *(const bf16x8*)(W1T +
              (size_t)(e * NH + colbase + 16 * mf + l15) * 96 + 32 * ks + 8 * l4);
#pragma unroll
        for (int mf = 0; mf < 2; ++mf)
#pragma unroll
          for (int nf = 0; nf < 4; ++nf)
            acc[mf][nf] = __builtin_amdgcn_mfma_f32_16x16x32_bf16(
                w1f[mf], bfr[nf][ks], acc[mf][nf], 0, 0, 0);
      }
      // epilogue: relu, scale by w[row], pack 4 consecutive hcols -> one b64 write
#pragma unroll
      for (int mf = 0; mf < 2; ++mf) {
        const int hcol = colbase + 16 * mf + 4 * l4;
#pragma unroll
        for (int nf = 0; nf < 4; ++nf) {
          float w = wv[nf];
          f32x4 a = acc[mf][nf];
          unsigned int p0 = (unsigned int)f2bf(fmaxf(a[0], 0.f) * w) |
                            ((unsigned int)f2bf(fmaxf(a[1], 0.f) * w) << 16);
          unsigned int p1 = (unsigned int)f2bf(fmaxf(a[2], 0.f) * w) |
                            ((unsigned int)f2bf(fmaxf(a[3], 0.f) * w) << 16);
          u32x2 pk;
          pk[0] = p0;
          pk[1] = p1;
          *(u32x2*)&sH[(16 * nf + l15) * HPITCH + hcol] = pk;
        }
      }
    }
    __syncthreads();  // sH (all 256 hcols) complete

    // ---- layer 2: out = h @ W2, K split across waves, accumulate over experts ----
#pragma unroll
    for (int ks2 = 0; ks2 < 2; ++ks2) {
      const int k = 64 * wid + 32 * ks2 + 8 * l4;
      bf16x8 bw = *(const bf16x8*)(W2T + (size_t)(e * 16 + l15) * NH + k);
#pragma unroll
      for (int rf = 0; rf < 4; ++rf) {
        bf16x8 ah = *(const bf16x8*)&sH[(16 * rf + l15) * HPITCH + k];
        facc[rf] = __builtin_amdgcn_mfma_f32_16x16x32_bf16(ah, bw, facc[rf], 0, 0, 0);
      }
    }
    __syncthreads();  // protect sH before next expert overwrites it
  }

  // ---- cross-wave reduction of layer-2 partials + store ----
  if (l15 < DO4) {
#pragma unroll
    for (int rf = 0; rf < 4; ++rf)
#pragma unroll
      for (int r = 0; r < 4; ++r)
        sOutP[wid][16 * rf + 4 * l4 + r][l15] = facc[rf][r];
  }
  __syncthreads();
  {
    const int row = t >> 2, o = t & 3;
    float v = sB2[row][o] + sOutP[0][row][o] + sOutP[1][row][o] +
              sOutP[2][row][o] + sOutP[3][row][o];
    out[(size_t)(row0 + row) * DO4 + o] = v;
  }
}

extern "C" void kernel_launch(void* const* d_in, const int* in_sizes, int n_in,
                              void* d_out, int out_size, void* d_ws, size_t ws_size,
                              hipStream_t stream) {
  const float* x    = (const float*)d_in[0];
  const float* cent = (const float*)d_in[1];
  const float* W1   = (const float*)d_in[2];
  const float* b1   = (const float*)d_in[3];
  const float* W2   = (const float*)d_in[4];
  const float* b2   = (const float*)d_in[5];
  float* out = (float*)d_out;

  unsigned short* W1T = (unsigned short*)d_ws;          // 8*256*96 bf16 = 393216 B
  unsigned short* W2T = W1T + NE * NH * 96;             // 8*16*256 bf16 = 65536 B

  prep_w1<<<(NE * NH * 96 + 255) / 256, 256, 0, stream>>>(W1, W1T);
  prep_w2<<<(NE * 16 * NH + 255) / 256, 256, 0, stream>>>(W2, W2T);
  meganerf_main<<<NPTS / 64, 256, 0, stream>>>(x, cent, b1, b2, W1T, W2T, out);
}

// Round 2
// 181.126 us; speedup vs baseline: 1.0686x; 1.0686x over previous
//
#include <hip/hip_runtime.h>

#define NPTS 131072
#define NE 8
#define DIN 90
#define NH 256
#define HPITCH 264   // bf16 elems per sH row (528 B, 16B-aligned rows)

typedef __attribute__((ext_vector_type(8))) short bf16x8;
typedef __attribute__((ext_vector_type(4))) float f32x4;
typedef __attribute__((ext_vector_type(2))) float f32x2;
typedef __attribute__((ext_vector_type(4))) unsigned int u32x4;
typedef __attribute__((ext_vector_type(2))) unsigned int u32x2;
typedef __attribute__((ext_vector_type(4), aligned(4))) float f32x4a;
typedef __attribute__((ext_vector_type(2), aligned(4))) float f32x2a;

// exact RNE (used only in weight prep, off the critical path)
__device__ __forceinline__ unsigned short f2bf(float f) {
  unsigned int u = __float_as_uint(f);
  u += 0x7fffu + ((u >> 16) & 1u);
  return (unsigned short)(u >> 16);
}

// fast pair-pack: round-to-nearest (ties-down) via +0x7fff, merge high halves
// with one v_perm_b32. 3 VALU insts per 2 elements vs ~11 for manual RNE pair.
__device__ __forceinline__ unsigned int pkbf(float f0, float f1) {
  unsigned int u0 = __float_as_uint(f0) + 0x7fffu;
  unsigned int u1 = __float_as_uint(f1) + 0x7fffu;
  return __builtin_amdgcn_perm(u1, u0, 0x07060302u);  // {u1.hi16, u0.hi16}
}

__device__ __forceinline__ bf16x8 cvt8(f32x4 a, f32x4 b) {
  u32x4 r;
  r[0] = pkbf(a[0], a[1]);
  r[1] = pkbf(a[2], a[3]);
  r[2] = pkbf(b[0], b[1]);
  r[3] = pkbf(b[2], b[3]);
  return __builtin_bit_cast(bf16x8, r);
}

// merged prep: W1 (E,DIN,H) -> W1T [e][hcol][k96] bf16 ; W2 (E,H,4) -> W2T [e][o16][k256] bf16
__global__ __launch_bounds__(256) void prep(const float* __restrict__ W1,
                                            const float* __restrict__ W2,
                                            unsigned short* __restrict__ W1T,
                                            unsigned short* __restrict__ W2T) {
  int idx = blockIdx.x * 256 + threadIdx.x;
  const int n1 = NE * NH * 96;
  if (idx < n1) {
    int kp = idx % 96;
    int n  = (idx / 96) % NH;
    int e  = idx / (96 * NH);
    float v = (kp < DIN) ? W1[((size_t)e * DIN + kp) * NH + n] : 0.f;
    W1T[idx] = f2bf(v);
  } else {
    int j = idx - n1;
    if (j < NE * 16 * NH) {
      int k = j % NH;
      int o = (j / NH) % 16;
      int e = j / (16 * NH);
      float v = (o < 4) ? W2[((size_t)e * NH + k) * 4 + o] : 0.f;
      W2T[j] = f2bf(v);
    }
  }
}

__global__ __launch_bounds__(256, 3) void meganerf_main(
    const float* __restrict__ x, const float* __restrict__ cent,
    const float* __restrict__ b1, const float* __restrict__ b2,
    const unsigned short* __restrict__ W1T, const unsigned short* __restrict__ W2T,
    float* __restrict__ out) {
  __shared__ unsigned short sH[64 * HPITCH];   // 33792 B; also reused as sOutP scratch
  __shared__ float sW[NE][64];                 // 2048 B
  __shared__ float sB2[64][4];                 // 1024 B   -> total 36864 B = 4 blocks/CU

  const int t    = threadIdx.x;
  const int lane = t & 63;
  const int wid  = t >> 6;
  const int l15  = lane & 15;
  const int l4   = lane >> 4;
  const int row0 = blockIdx.x * 64;

  // ---- feat fragments (MFMA B operand B[k][n=row]), kept in regs across all experts ----
  bf16x8 bfr[4][3];
#pragma unroll
  for (int nf = 0; nf < 4; ++nf) {
    const float* gr = x + (size_t)(row0 + 16 * nf + l15) * 93 + 3;
    f32x4 v0, v1;
    v0 = *(const f32x4a*)(gr + 8 * l4);
    v1 = *(const f32x4a*)(gr + 8 * l4 + 4);
    bfr[nf][0] = cvt8(v0, v1);
    v0 = *(const f32x4a*)(gr + 32 + 8 * l4);
    v1 = *(const f32x4a*)(gr + 36 + 8 * l4);
    bfr[nf][1] = cvt8(v0, v1);
    if (l4 < 3) {
      v0 = *(const f32x4a*)(gr + 64 + 8 * l4);
      v1 = *(const f32x4a*)(gr + 68 + 8 * l4);
    } else {
      f32x2 tl = *(const f32x2a*)(gr + 88);   // k=88,89 valid; 90..95 are zero pad
      v0[0] = tl[0]; v0[1] = tl[1]; v0[2] = 0.f; v0[3] = 0.f;
      v1[0] = 0.f; v1[1] = 0.f; v1[2] = 0.f; v1[3] = 0.f;
    }
    bfr[nf][2] = cvt8(v0, v1);
  }

  // ---- per-point expert weights ----
  if (t < 64) {
    const float* gx = x + (size_t)(row0 + t) * 93;
    float px = gx[0], py = gx[1], pz = gx[2];
    float dist[NE], inv[NE];
    float mind = 3.4e38f;
#pragma unroll
    for (int e = 0; e < NE; ++e) {
      float dx = px - cent[e * 3 + 0];
      float dy = py - cent[e * 3 + 1];
      float dz = pz - cent[e * 3 + 2];
      float d2 = dx * dx + dy * dy + dz * dz;
      float d = sqrtf(fmaxf(d2, 0.f));
      dist[e] = d;
      inv[e] = 1.f / (d + 1e-8f);
      mind = fminf(mind, d);
    }
    float s = 0.f;
#pragma unroll
    for (int e = 0; e < NE; ++e) {
      if (dist[e] > 2.0f * mind) inv[e] = 0.f;
      s += inv[e];
    }
    float rs = 1.f / s;
    float bb[4] = {0.f, 0.f, 0.f, 0.f};
#pragma unroll
    for (int e = 0; e < NE; ++e) {
      float w = inv[e] * rs;
      sW[e][t] = w;
#pragma unroll
      for (int o = 0; o < 4; ++o) bb[o] += w * b2[e * 4 + o];
    }
#pragma unroll
    for (int o = 0; o < 4; ++o) sB2[t][o] = bb[o];
  }
  __syncthreads();

  f32x4 facc[4] = {{0.f, 0.f, 0.f, 0.f}, {0.f, 0.f, 0.f, 0.f},
                   {0.f, 0.f, 0.f, 0.f}, {0.f, 0.f, 0.f, 0.f}};

  for (int e = 0; e < NE; ++e) {
    float wv[4];
#pragma unroll
    for (int nf = 0; nf < 4; ++nf) wv[nf] = sW[e][16 * nf + l15];

    // ---- layer 1: h^T = W1^T * feat^T ----
#pragma unroll
    for (int c = 0; c < 2; ++c) {
      const int colbase = 128 * c + 32 * wid;
      f32x4 b1v[2];
#pragma unroll
      for (int mf = 0; mf < 2; ++mf)
        b1v[mf] = *(const f32x4*)(b1 + e * NH + colbase + 16 * mf + 4 * l4);
      f32x4 acc[2][4];
#pragma unroll
      for (int mf = 0; mf < 2; ++mf)
#pragma unroll
        for (int nf = 0; nf < 4; ++nf) acc[mf][nf] = b1v[mf];
#pragma unroll
      for (int ks = 0; ks < 3; ++ks) {
        bf16x8 w1f[2];
#pragma unroll
        for (int mf = 0; mf < 2; ++mf)
          w1f[mf] = *(const bf16x8*)(W1T +
              (size_t)(e * NH + colbase + 16 * mf + l15) * 96 + 32 * ks + 8 * l4);
#pragma unroll
        for (int mf = 0; mf < 2; ++mf)
#pragma unroll
          for (int nf = 0; nf < 4; ++nf)
            acc[mf][nf] = __builtin_amdgcn_mfma_f32_16x16x32_bf16(
                w1f[mf], bfr[nf][ks], acc[mf][nf], 0, 0, 0);
      }
      // epilogue: packed relu*w, 3-inst pair-pack, one b64 LDS write per frag
#pragma unroll
      for (int mf = 0; mf < 2; ++mf) {
        const int hcol = colbase + 16 * mf + 4 * l4;
#pragma unroll
        for (int nf = 0; nf < 4; ++nf) {
          const float w = wv[nf];
          f32x4 a = acc[mf][nf];
          f32x2 p0, p1;
          p0[0] = a[0]; p0[1] = a[1];
          p1[0] = a[2]; p1[1] = a[3];
          const f32x2 z = {0.f, 0.f};
          p0 = __builtin_elementwise_max(p0, z) * w;
          p1 = __builtin_elementwise_max(p1, z) * w;
          u32x2 pk;
          pk[0] = pkbf(p0[0], p0[1]);
          pk[1] = pkbf(p1[0], p1[1]);
          *(u32x2*)&sH[(16 * nf + l15) * HPITCH + hcol] = pk;
        }
      }
    }
    __syncthreads();

    // ---- layer 2: out += h @ W2 (o padded to 16), K split across waves ----
#pragma unroll
    for (int ks2 = 0; ks2 < 2; ++ks2) {
      const int k = 64 * wid + 32 * ks2 + 8 * l4;
      bf16x8 bw = *(const bf16x8*)(W2T + (size_t)(e * 16 + l15) * NH + k);
#pragma unroll
      for (int rf = 0; rf < 4; ++rf) {
        bf16x8 ah = *(const bf16x8*)&sH[(16 * rf + l15) * HPITCH + k];
        facc[rf] = __builtin_amdgcn_mfma_f32_16x16x32_bf16(ah, bw, facc[rf], 0, 0, 0);
      }
    }
    __syncthreads();
  }

  // ---- cross-wave reduction (sOutP aliased onto sH, dead after last barrier) ----
  float* sOutP = (float*)sH;   // [wid][row][o] = ((wid*64+row)*4+o)
  if (l15 < 4) {
#pragma unroll
    for (int rf = 0; rf < 4; ++rf)
#pragma unroll
      for (int r = 0; r < 4; ++r)
        sOutP[(wid * 64 + 16 * rf + 4 * l4 + r) * 4 + l15] = facc[rf][r];
  }
  __syncthreads();
  {
    const int row = t >> 2, o = t & 3;
    float v = sB2[row][o] + sOutP[(0 * 64 + row) * 4 + o] + sOutP[(1 * 64 + row) * 4 + o] +
              sOutP[(2 * 64 + row) * 4 + o] + sOutP[(3 * 64 + row) * 4 + o];
    out[row0 * 4 + t] = v;
  }
}

extern "C" void kernel_launch(void* const* d_in, const int* in_sizes, int n_in,
                              void* d_out, int out_size, void* d_ws, size_t ws_size,
                              hipStream_t stream) {
  const float* x    = (const float*)d_in[0];
  const float* cent = (const float*)d_in[1];
  const float* W1   = (const float*)d_in[2];
  const float* b1   = (const float*)d_in[3];
  const float* W2   = (const float*)d_in[4];
  const float* b2   = (const float*)d_in[5];
  float* out = (float*)d_out;

  unsigned short* W1T = (unsigned short*)d_ws;   // 393216 B
  unsigned short* W2T = W1T + NE * NH * 96;      // 65536 B

  const int prep_total = NE * NH * 96 + NE * 16 * NH;
  prep<<<(prep_total + 255) / 256, 256, 0, stream>>>(W1, W2, W1T, W2T);
  meganerf_main<<<NPTS / 64, 256, 0, stream>>>(x, cent, b1, b2, W1T, W2T, out);
}

// Round 3
// 168.053 us; speedup vs baseline: 1.1517x; 1.0778x over previous
//
#include <hip/hip_runtime.h>

#define NPTS 131072
#define NE 8
#define DIN 90
#define NH 256

typedef __attribute__((ext_vector_type(8))) short bf16x8;
typedef __attribute__((ext_vector_type(4))) float f32x4;
typedef __attribute__((ext_vector_type(2))) float f32x2;
typedef __attribute__((ext_vector_type(4))) unsigned int u32x4;
typedef __attribute__((ext_vector_type(2))) unsigned int u32x2;
typedef __attribute__((ext_vector_type(4), aligned(4))) float f32x4a;
typedef __attribute__((ext_vector_type(2), aligned(4))) float f32x2a;

// exact RNE (prep only)
__device__ __forceinline__ unsigned short f2bf(float f) {
  unsigned int u = __float_as_uint(f);
  u += 0x7fffu + ((u >> 16) & 1u);
  return (unsigned short)(u >> 16);
}

// fast pair-pack: +0x7fff (ties-down) then one v_perm_b32 merging high halves
__device__ __forceinline__ unsigned int pkbf(float f0, float f1) {
  unsigned int u0 = __float_as_uint(f0) + 0x7fffu;
  unsigned int u1 = __float_as_uint(f1) + 0x7fffu;
  return __builtin_amdgcn_perm(u1, u0, 0x07060302u);  // {u1.hi16, u0.hi16}
}

__device__ __forceinline__ bf16x8 cvt8(f32x4 a, f32x4 b) {
  u32x4 r;
  r[0] = pkbf(a[0], a[1]);
  r[1] = pkbf(a[2], a[3]);
  r[2] = pkbf(b[0], b[1]);
  r[3] = pkbf(b[2], b[3]);
  return __builtin_bit_cast(bf16x8, r);
}

// prep, coalesced reads / scattered writes:
//  seg0: W1 (E,DIN,H) -> W1T [e][hcol][k96]      (184320 threads)
//  seg1: zero W1T k=90..95 pad                   (12288)
//  seg2: W2 (E,H,4)  -> W2T [e][o16][k256], o<4  (8192)
//  seg3: zero W2T o=4..15 pad                    (24576)
#define PREP_T (184320 + 12288 + 8192 + 24576)
__global__ __launch_bounds__(256) void prep(const float* __restrict__ W1,
                                            const float* __restrict__ W2,
                                            unsigned short* __restrict__ W1T,
                                            unsigned short* __restrict__ W2T) {
  int tid = blockIdx.x * 256 + threadIdx.x;
  if (tid < 184320) {
    float v = W1[tid];                    // coalesced
    int n = tid & 255, r = tid >> 8;      // r = e*90+kp
    int kp = r % 90, e = r / 90;
    W1T[(size_t)(e * NH + n) * 96 + kp] = f2bf(v);
    return;
  }
  tid -= 184320;
  if (tid < 12288) {
    int kp = 90 + tid % 6, q = tid / 6;
    int n = q & 255, e = q >> 8;
    W1T[(size_t)(e * NH + n) * 96 + kp] = 0;
    return;
  }
  tid -= 12288;
  if (tid < 8192) {
    float v = W2[tid];                    // coalesced
    int o = tid & 3, k = (tid >> 2) & 255, e = tid >> 10;
    W2T[(size_t)(e * 16 + o) * NH + k] = f2bf(v);
    return;
  }
  tid -= 8192;
  if (tid < 24576) {
    int k = tid & 255, q = tid >> 8;
    int o = 4 + q % 12, e = q / 12;
    W2T[(size_t)(e * 16 + o) * NH + k] = 0;
  }
}

__global__ __launch_bounds__(256, 3) void meganerf_main(
    const float* __restrict__ x, const float* __restrict__ cent,
    const float* __restrict__ b1, const float* __restrict__ b2,
    const unsigned short* __restrict__ W1T, const unsigned short* __restrict__ W2T,
    float* __restrict__ out) {
  // Wave-PRIVATE h staging in exact layer-2 A-fragment order:
  //   sH[wid*4096 + ((rf*2+ks2)*64 + lane)*8 + j]
  // -> layer-2 ds_read_b128 is lane-contiguous (0 conflicts), the producer
  //    ds_write_b64 fills contiguous 512B regions (<=2-way). No barriers in
  //    the expert loop: each wave consumes only h it produced.
  __shared__ unsigned short sH[4 * 4096];  // 32768 B (reused as sOutP at end)
  __shared__ float sW[NE][64];             // 2048 B
  __shared__ float sB2[64][4];             // 1024 B  -> 35840 B total

  const int t    = threadIdx.x;
  const int lane = t & 63;
  const int wid  = t >> 6;
  const int l15  = lane & 15;
  const int l4   = lane >> 4;
  const int row0 = blockIdx.x * 64;
  const int gbase = wid * 4096;

  // ---- feat fragments (MFMA B operand B[k][n=row]), regs for all experts ----
  bf16x8 bfr[4][3];
#pragma unroll
  for (int nf = 0; nf < 4; ++nf) {
    const float* gr = x + (size_t)(row0 + 16 * nf + l15) * 93 + 3;
    f32x4 v0, v1;
    v0 = *(const f32x4a*)(gr + 8 * l4);
    v1 = *(const f32x4a*)(gr + 8 * l4 + 4);
    bfr[nf][0] = cvt8(v0, v1);
    v0 = *(const f32x4a*)(gr + 32 + 8 * l4);
    v1 = *(const f32x4a*)(gr + 36 + 8 * l4);
    bfr[nf][1] = cvt8(v0, v1);
    if (l4 < 3) {
      v0 = *(const f32x4a*)(gr + 64 + 8 * l4);
      v1 = *(const f32x4a*)(gr + 68 + 8 * l4);
    } else {
      f32x2 tl = *(const f32x2a*)(gr + 88);   // k=88,89 valid; rest zero pad
      v0[0] = tl[0]; v0[1] = tl[1]; v0[2] = 0.f; v0[3] = 0.f;
      v1[0] = 0.f; v1[1] = 0.f; v1[2] = 0.f; v1[3] = 0.f;
    }
    bfr[nf][2] = cvt8(v0, v1);
  }

  // ---- per-point expert weights ----
  if (t < 64) {
    const float* gx = x + (size_t)(row0 + t) * 93;
    float px = gx[0], py = gx[1], pz = gx[2];
    float dist[NE], inv[NE];
    float mind = 3.4e38f;
#pragma unroll
    for (int e = 0; e < NE; ++e) {
      float dx = px - cent[e * 3 + 0];
      float dy = py - cent[e * 3 + 1];
      float dz = pz - cent[e * 3 + 2];
      float d2 = dx * dx + dy * dy + dz * dz;
      float d = sqrtf(fmaxf(d2, 0.f));
      dist[e] = d;
      inv[e] = 1.f / (d + 1e-8f);
      mind = fminf(mind, d);
    }
    float s = 0.f;
#pragma unroll
    for (int e = 0; e < NE; ++e) {
      if (dist[e] > 2.0f * mind) inv[e] = 0.f;
      s += inv[e];
    }
    float rs = 1.f / s;
    float bb[4] = {0.f, 0.f, 0.f, 0.f};
#pragma unroll
    for (int e = 0; e < NE; ++e) {
      float w = inv[e] * rs;
      sW[e][t] = w;
#pragma unroll
      for (int o = 0; o < 4; ++o) bb[o] += w * b2[e * 4 + o];
    }
#pragma unroll
    for (int o = 0; o < 4; ++o) sB2[t][o] = bb[o];
  }
  __syncthreads();   // the only barrier before the tail

  f32x4 facc[4] = {{0.f, 0.f, 0.f, 0.f}, {0.f, 0.f, 0.f, 0.f},
                   {0.f, 0.f, 0.f, 0.f}, {0.f, 0.f, 0.f, 0.f}};

  for (int e = 0; e < NE; ++e) {
    // hoist independent global loads to the top of the iteration
    bf16x8 bw[2];
#pragma unroll
    for (int ks2 = 0; ks2 < 2; ++ks2)
      bw[ks2] = *(const bf16x8*)(W2T + (size_t)(e * 16 + l15) * NH +
                                 128 * ks2 + 32 * wid + 8 * l4);
    float wv[4];
#pragma unroll
    for (int nf = 0; nf < 4; ++nf) wv[nf] = sW[e][16 * nf + l15];

    // ---- layer 1: h^T = W1^T * feat^T, this wave's 64 hcols ----
#pragma unroll
    for (int c = 0; c < 2; ++c) {
      const int colbase = 128 * c + 32 * wid;
      bf16x8 w1f[2][3];
#pragma unroll
      for (int ks = 0; ks < 3; ++ks)
#pragma unroll
        for (int mf = 0; mf < 2; ++mf)
          w1f[mf][ks] = *(const bf16x8*)(W1T +
              (size_t)(e * NH + colbase + 16 * mf + l15) * 96 + 32 * ks + 8 * l4);
      f32x4 b1v[2];
#pragma unroll
      for (int mf = 0; mf < 2; ++mf)
        b1v[mf] = *(const f32x4*)(b1 + e * NH + colbase + 16 * mf + 4 * l4);
      f32x4 acc[2][4];
#pragma unroll
      for (int mf = 0; mf < 2; ++mf)
#pragma unroll
        for (int nf = 0; nf < 4; ++nf) acc[mf][nf] = b1v[mf];
#pragma unroll
      for (int ks = 0; ks < 3; ++ks)
#pragma unroll
        for (int mf = 0; mf < 2; ++mf)
#pragma unroll
          for (int nf = 0; nf < 4; ++nf)
            acc[mf][nf] = __builtin_amdgcn_mfma_f32_16x16x32_bf16(
                w1f[mf][ks], bfr[nf][ks], acc[mf][nf], 0, 0, 0);

      // epilogue: relu*w, pack, store into A-frag-order private region.
      // element (row=16nf+l15, localcol=32c+16mf+4l4+r) -> region (rf=nf,ks2=c),
      // granule l15+16*(2mf+(l4>>1)), slot 4*(l4&1)+r
#pragma unroll
      for (int mf = 0; mf < 2; ++mf) {
#pragma unroll
        for (int nf = 0; nf < 4; ++nf) {
          const float w = wv[nf];
          f32x4 a = acc[mf][nf];
          f32x2 p0, p1;
          p0[0] = a[0]; p0[1] = a[1];
          p1[0] = a[2]; p1[1] = a[3];
          const f32x2 z = {0.f, 0.f};
          p0 = __builtin_elementwise_max(p0, z) * w;
          p1 = __builtin_elementwise_max(p1, z) * w;
          u32x2 pk;
          pk[0] = pkbf(p0[0], p0[1]);
          pk[1] = pkbf(p1[0], p1[1]);
          *(u32x2*)&sH[gbase + ((nf * 2 + c) * 64 + (l15 + 16 * (2 * mf + (l4 >> 1)))) * 8 +
                       4 * (l4 & 1)] = pk;
        }
      }
    }

    // ---- layer 2 (wave-private, no barrier): facc += h @ W2 over our hcols ----
#pragma unroll
    for (int ks2 = 0; ks2 < 2; ++ks2)
#pragma unroll
      for (int rf = 0; rf < 4; ++rf) {
        bf16x8 ah = *(const bf16x8*)&sH[gbase + ((rf * 2 + ks2) * 64 + lane) * 8];
        facc[rf] = __builtin_amdgcn_mfma_f32_16x16x32_bf16(ah, bw[ks2], facc[rf], 0, 0, 0);
      }
  }

  // ---- cross-wave reduction (sOutP aliased onto sH) ----
  __syncthreads();   // all waves done with their sH regions
  float* sOutP = (float*)sH;   // [wid][row][o]
  if (l15 < 4) {
#pragma unroll
    for (int rf = 0; rf < 4; ++rf)
#pragma unroll
      for (int r = 0; r < 4; ++r)
        sOutP[(wid * 64 + 16 * rf + 4 * l4 + r) * 4 + l15] = facc[rf][r];
  }
  __syncthreads();
  {
    const int row = t >> 2, o = t & 3;
    float v = sB2[row][o] + sOutP[(0 * 64 + row) * 4 + o] + sOutP[(1 * 64 + row) * 4 + o] +
              sOutP[(2 * 64 + row) * 4 + o] + sOutP[(3 * 64 + row) * 4 + o];
    out[row0 * 4 + t] = v;
  }
}

extern "C" void kernel_launch(void* const* d_in, const int* in_sizes, int n_in,
                              void* d_out, int out_size, void* d_ws, size_t ws_size,
                              hipStream_t stream) {
  const float* x    = (const float*)d_in[0];
  const float* cent = (const float*)d_in[1];
  const float* W1   = (const float*)d_in[2];
  const float* b1   = (const float*)d_in[3];
  const float* W2   = (const float*)d_in[4];
  const float* b2   = (const float*)d_in[5];
  float* out = (float*)d_out;

  unsigned short* W1T = (unsigned short*)d_ws;   // 393216 B
  unsigned short* W2T = W1T + NE * NH * 96;      // 65536 B

  prep<<<(PREP_T + 255) / 256, 256, 0, stream>>>(W1, W2, W1T, W2T);
  meganerf_main<<<NPTS / 64, 256, 0, stream>>>(x, cent, b1, b2, W1T, W2T, out);
}